// Round 1
// 239.946 us; speedup vs baseline: 1.0530x; 1.0530x over previous
//
#include <hip/hip_runtime.h>

// LoG: GaussianBlur(3x3, sigma=1, BORDER_REFLECT_101) -> Laplacian(ksize=9) -> +1 -> clip[0,255]
// x: [32,512,512,3] float32 NHWC. out: same.
//
// Laplacian 9x9 kernel = outer(S9,D9)+outer(D9,S9) -> two separable passes:
//   t1 = vert(S9, blur); t2 = vert(D9, blur); out = horz(D9,t1) + horz(S9,t2) + 1
// Reflect-101 is applied at EACH stage in the reference; boundary blur values are
// blur[reflect(g)] where blur itself read x[reflect(.)] -- handled exactly via
// inline double-reflect row indices (stage 2) and column LUT fallback (stage 1,
// edge-column blocks only).
//
// Tile 32x16 (was 32x32): LDS peak 26,880 B -> 6 blocks/CU (24 waves, 75% occ
// ceiling) vs previous 50,688 B -> 3 blocks (37.5%).

#define TH 16
#define TW 32
#define FW (TW*3)        // 96 output floats per tile row
#define BF ((TW+8)*3)    // 120 floats per blur/hblur row (±4 px halo)
#define BH (TH+8)        // 24 blur rows
#define HIMG 512
#define WIMG 512
#define ROWF (WIMG*3)    // 1536 floats per image row

// LDS float layout (single buffer, aliased by stage):
//   [0, 3840)    : hblur (<=26 rows x 120 = 3120) during stages 1-2;
//                  t1 [0,1920) + t2 [1920,3840) during stage 3 (hblur dead)
//   [3840, 6720) : blur (24 x 120 = 2880)
#define SM_TOTAL 6720    // 26,880 B; +512B rounding stays under 163840/6

__device__ __forceinline__ int reflect101(int i, int n) {
    i = (i < 0) ? -i : i;
    return (i >= n) ? (2 * n - 2 - i) : i;
}

__device__ __forceinline__ float4 fma4(float s, const float4& a, const float4& b) {
    return make_float4(fmaf(s, a.x, b.x), fmaf(s, a.y, b.y),
                       fmaf(s, a.z, b.z), fmaf(s, a.w, b.w));
}

__global__ __launch_bounds__(256, 6)
void log_fused(const float* __restrict__ x, float* __restrict__ out) {
    __shared__ __align__(16) float smem[SM_TOTAL];
    float* const hblur = smem;
    float* const t1    = smem;
    float* const t2    = smem + TH * BF;       // +1920
    float* const blur  = smem + 2 * TH * BF;   // +3840

    const int tid  = threadIdx.x;
    const int col0 = blockIdx.x * TW;
    const int row0 = blockIdx.y * TH;
    const int n    = blockIdx.z;

    const int R0    = max(0, row0 - 5);
    const int R1    = min(HIMG - 1, row0 + TH + 4);
    const int nrows = R1 - R0 + 1;   // <= 26; all double-reflected rows land in [R0,R1]

    const float G0 = 0.2740686190f, G1 = 0.4518627620f;  // normalized exp(-{1,0,1}/2)

    // ---- stage 1: horizontal 3-tap Gaussian, global -> hblur ----
    const bool edgecol = (col0 == 0) || (col0 + TW == WIMG);
    if (!edgecol) {
        // Interior columns: no horizontal reflect possible -> vectorized path.
        // Thread (cg, rg): cg owns hblur float4 chunk [4cg,4cg+4), rg strides rows by 8.
        // hblur float lc maps to x float xf = 3*(col0-4) + lc; we load the aligned
        // 12-float window starting at xf(4cg) - 4 (alignment: 3*col0 ≡ 0 mod 4).
        if (tid < 240) {
            const int cg = tid % 30;
            const int rg = tid / 30;            // 0..7
            const float* xb = x + ((size_t)n * HIMG + (size_t)(R0 + rg)) * ROWF
                                + (3 * (col0 - 4) + 4 * cg - 4);
            float* hb = hblur + rg * BF + 4 * cg;
            for (int r = rg; r < nrows; r += 8, xb += 8 * ROWF, hb += 8 * BF) {
                const float4 a = *(const float4*)(xb);
                const float4 b = *(const float4*)(xb + 4);
                const float4 c = *(const float4*)(xb + 8);
                // f[0..11]=a,b,c; out[j] = G0*(f[j+1]+f[j+7]) + G1*f[j+4]
                float4 o;
                o.x = G0 * (a.y + b.w) + G1 * b.x;
                o.y = G0 * (a.z + c.x) + G1 * b.y;
                o.z = G0 * (a.w + c.y) + G1 * b.z;
                o.w = G0 * (b.x + c.z) + G1 * b.w;
                *(float4*)hb = o;
            }
        }
    } else {
        // Edge-column blocks (2/16): scalar column-LUT path with double-reflect.
        if (tid < 240) {
            const int lc  = tid % BF;
            const int rg  = tid / BF;           // 0 or 1
            const int lcp = lc / 3;
            const int ch  = lc - 3 * lcp;
            const int gc  = reflect101(col0 - 4 + lcp, WIMG);
            const int xm  = reflect101(gc - 1, WIMG) * 3 + ch;
            const int x0  = gc * 3 + ch;
            const int xp  = reflect101(gc + 1, WIMG) * 3 + ch;
            const float* xr = x + ((size_t)n * HIMG + (size_t)(R0 + rg)) * ROWF;
            for (int r = rg; r < nrows; r += 2, xr += 2 * ROWF) {
                hblur[r * BF + lc] = G0 * (xr[xm] + xr[xp]) + G1 * xr[x0];
            }
        }
    }
    __syncthreads();

    // ---- stage 2: vertical 3-tap Gaussian with inline double-reflect rows ----
    for (int e = tid; e < BH * (BF / 4); e += 256) {   // 720 groups
        const int lr = e % BH;
        const int qc = e / BH;                 // 0..29
        const int gr = reflect101(row0 - 4 + lr, HIMG);
        const int rm = reflect101(gr - 1, HIMG) - R0;
        const int rz = gr - R0;
        const int rp = reflect101(gr + 1, HIMG) - R0;
        const int lc = qc * 4;
        const float4 a = *(const float4*)&hblur[rm * BF + lc];
        const float4 b = *(const float4*)&hblur[rz * BF + lc];
        const float4 c = *(const float4*)&hblur[rp * BF + lc];
        float4 r;
        r.x = G0 * (a.x + c.x) + G1 * b.x;
        r.y = G0 * (a.y + c.y) + G1 * b.y;
        r.z = G0 * (a.z + c.z) + G1 * b.z;
        r.w = G0 * (a.w + c.w) + G1 * b.w;
        *(float4*)&blur[lr * BF + lc] = r;
    }
    __syncthreads();   // hblur dead beyond this point; t1/t2 overwrite it

    const float S9[9] = {1.f, 8.f, 28.f, 56.f, 70.f, 56.f, 28.f, 8.f, 1.f};
    const float D9[9] = {1.f, 4.f, 4.f, -4.f, -10.f, -4.f, 4.f, 4.f, 1.f};

    // ---- stage 3a: vertical 9-tap S and D, blur -> t1,t2 (2-row register block) ----
    // rg = tid&7 varies fastest across lanes -> row-pair chunk bases spaced 4 banks.
    if (tid < 240) {                          // (TH/2)*(BF/4) = 240 groups exactly
        const int rg  = tid & 7;
        const int qc  = tid >> 3;             // 0..29
        const int lr0 = rg * 2;
        const int lc  = qc * 4;
        float4 w[10];
        #pragma unroll
        for (int k = 0; k < 10; ++k)
            w[k] = *(const float4*)&blur[(lr0 + k) * BF + lc];
        float4 a1r0 = make_float4(0.f, 0.f, 0.f, 0.f), a2r0 = a1r0;
        float4 a1r1 = a1r0, a2r1 = a1r0;
        #pragma unroll
        for (int k = 0; k < 9; ++k) {
            a1r0 = fma4(S9[k], w[k],     a1r0);
            a2r0 = fma4(D9[k], w[k],     a2r0);
            a1r1 = fma4(S9[k], w[k + 1], a1r1);
            a2r1 = fma4(D9[k], w[k + 1], a2r1);
        }
        *(float4*)&t1[(lr0    ) * BF + lc] = a1r0;
        *(float4*)&t1[(lr0 + 1) * BF + lc] = a1r1;
        *(float4*)&t2[(lr0    ) * BF + lc] = a2r0;
        *(float4*)&t2[(lr0 + 1) * BF + lc] = a2r1;
    }
    __syncthreads();

    // ---- stage 3b: horizontal 9-tap D(t1)+S(t2), +1, clip, store ----
    // 4-output groups: per-lane window is 7 CONSECUTIVE f4 chunks -> lanes cover
    // consecutive banks (~2-way max, free) instead of the old stride-2-chunk
    // pattern (even banks only, ~4-5-way).
    float* const outn = out + (size_t)n * HIMG * ROWF;
    for (int g = tid; g < TH * (FW / 4); g += 256) {   // 384 groups of 4 outputs
        const int lr = g / (FW / 4 / 1 * 1 / 16 * 16 == 0 ? 1 : 24); // placeholder avoided
        (void)lr;
        const int lr2 = g / 24;               // 24 lanes per row: good store runs
        const int qp  = g - lr2 * 24;         // 0..23
        const int c0  = qp * 4;               // out float base; window t[c0, c0+28)
        const float* t1r = t1 + lr2 * BF + c0;
        const float* t2r = t2 + lr2 * BF + c0;
        float acc[4] = {1.0f, 1.0f, 1.0f, 1.0f};   // delta = 1
        #pragma unroll
        for (int i = 0; i < 7; ++i) {
            const float4 v1 = *(const float4*)(t1r + 4 * i);
            const float4 v2 = *(const float4*)(t2r + 4 * i);
            const float f1[4] = {v1.x, v1.y, v1.z, v1.w};
            const float f2[4] = {v2.x, v2.y, v2.z, v2.w};
            #pragma unroll
            for (int m = 0; m < 4; ++m) {
                const int pos = 4 * i + m;     // compile-time after unroll
                const int j0  = pos % 3;
                const int k0  = pos / 3;
                if (k0 <= 8)
                    acc[j0] = fmaf(D9[k0], f1[m], fmaf(S9[k0], f2[m], acc[j0]));
                if (j0 == 0 && pos >= 3) {
                    const int k1 = k0 - 1;     // tap for output 3 (= pos - 3 - 3*k1)
                    acc[3] = fmaf(D9[k1], f1[m], fmaf(S9[k1], f2[m], acc[3]));
                }
            }
        }
        float4 o;
        o.x = fminf(fmaxf(acc[0], 0.0f), 255.0f);
        o.y = fminf(fmaxf(acc[1], 0.0f), 255.0f);
        o.z = fminf(fmaxf(acc[2], 0.0f), 255.0f);
        o.w = fminf(fmaxf(acc[3], 0.0f), 255.0f);
        float* op = outn + (size_t)(row0 + lr2) * ROWF + (size_t)(col0 * 3 + c0);
        *(float4*)op = o;
    }
}

extern "C" void kernel_launch(void* const* d_in, const int* in_sizes, int n_in,
                              void* d_out, int out_size, void* d_ws, size_t ws_size,
                              hipStream_t stream) {
    const float* x = (const float*)d_in[0];
    float* outp = (float*)d_out;
    const int nimg = in_sizes[0] / (HIMG * WIMG * 3);
    dim3 grid(WIMG / TW, HIMG / TH, nimg);
    log_fused<<<grid, dim3(256, 1, 1), 0, stream>>>(x, outp);
}

// Round 2
// 223.148 us; speedup vs baseline: 1.1322x; 1.0753x over previous
//
#include <hip/hip_runtime.h>

// LoG: GaussianBlur(3x3, sigma=1, BORDER_REFLECT_101) -> Laplacian(ksize=9) -> +1 -> clip[0,255]
// x: [32,512,512,3] float32 NHWC. out: same.
//
// Factorization: S9 = C6*[1,2,1], D9 = C6*[1,-2,1], C6 = {1,6,15,20,15,6,1}
//   lap = outer(S9,D9)+outer(D9,S9) = (C6 (x) C6) o [[2,0,2],[0,-8,0],[2,0,2]]
// so: out = cross3(P) + 1, P = vert7(C6, horz7... (here: horz after vert) of blur.
// One 7-tap per axis + 5-point cross replaces two 9-tap passes over two arrays.
// blur tile has +-4 px double-reflected halo (exact per-stage reflect-101), which
// covers 7-tap (+-3) + cross (+-1): stages 3a/3b/3c need no boundary logic.
//
// Bank discipline: per-instruction lane bank-quad bases must cover all 8 quads.
// blur/hblur rows: 120 floats (30 quads); chunk-fastest lane maps -> even.
// vq rows: 124 floats (31 quads, ODD) and P rows: 108 floats (27 quads, ODD) so
// 8-output groups (stride-2 chunk bases, even quads only) get odd per-row quad
// shifts -> even coverage. (R1's 1.88e7 conflicts = ~30us/dispatch came from
// multiple-of-8 quad bases covering only 4 quads.)

#define TH 16
#define TW 32
#define FW (TW*3)        // 96 output floats per tile row
#define BF ((TW+8)*3)    // 120 floats per hblur/blur row (+-4 px halo)
#define BH (TH+8)        // 24 blur rows
#define PH (TH+2)        // 18 vq/P rows (out rows -1..16)
#define VW 124           // vq row stride
#define PW 108           // P row stride
#define HIMG 512
#define WIMG 512
#define ROWF (WIMG*3)    // 1536 floats per image row

// LDS floats: A [0,3120): hblur(<=26x120) -> vq(18x124=2232)
//             B [3120,6000): blur(24x120=2880) -> P(18x108=1944)
#define OFF_B 3120
#define SM_TOTAL 6000    // 24000 B -> 6 blocks/CU

__device__ __forceinline__ int reflect101(int i, int n) {
    i = (i < 0) ? -i : i;
    return (i >= n) ? (2 * n - 2 - i) : i;
}

__device__ __forceinline__ float c6dot(float f0, float f1, float f2, float f3,
                                       float f4, float f5, float f6) {
    // {1,6,15,20,15,6,1} symmetric: 3 adds + 3 fma
    return fmaf(20.f, f3, fmaf(6.f, f1 + f5, fmaf(15.f, f2 + f4, f0 + f6)));
}

__device__ __forceinline__ float4 c6dot4(const float4& a, const float4& b, const float4& c,
                                         const float4& d, const float4& e, const float4& f,
                                         const float4& g) {
    return make_float4(c6dot(a.x, b.x, c.x, d.x, e.x, f.x, g.x),
                       c6dot(a.y, b.y, c.y, d.y, e.y, f.y, g.y),
                       c6dot(a.z, b.z, c.z, d.z, e.z, f.z, g.z),
                       c6dot(a.w, b.w, c.w, d.w, e.w, f.w, g.w));
}

__device__ __forceinline__ float4 g3(const float4& a, const float4& b, const float4& c,
                                     float G0, float G1) {
    return make_float4(G0 * (a.x + c.x) + G1 * b.x,
                       G0 * (a.y + c.y) + G1 * b.y,
                       G0 * (a.z + c.z) + G1 * b.z,
                       G0 * (a.w + c.w) + G1 * b.w);
}

__global__ __launch_bounds__(256, 6)
void log_fused(const float* __restrict__ x, float* __restrict__ out) {
    __shared__ __align__(16) float smem[SM_TOTAL];
    float* const hblur = smem;           // 26 x 120
    float* const vq    = smem;           // 18 x 124 (aliases hblur, after it's dead)
    float* const blur  = smem + OFF_B;   // 24 x 120
    float* const P     = smem + OFF_B;   // 18 x 108 (aliases blur, after it's dead)

    const int tid  = threadIdx.x;
    const int col0 = blockIdx.x * TW;
    const int row0 = blockIdx.y * TH;
    const int n    = blockIdx.z;

    const int R0    = max(0, row0 - 5);
    const int R1    = min(HIMG - 1, row0 + TH + 4);
    const int nrows = R1 - R0 + 1;   // <= 26

    const float G0 = 0.2740686190f, G1 = 0.4518627620f;  // normalized exp(-{1,0,1}/2)

    // ---- stage 1: horizontal 3-tap Gaussian, global -> hblur ----
    const bool edgecol = (col0 == 0) || (col0 + TW == WIMG);
    if (!edgecol) {
        // Interior columns: vectorized. 3*col0 % 4 == 0 so the 12-float window
        // starting at x-float 3*(col0-4)+4*cg-4 is 16B aligned.
        if (tid < 240) {
            const int cg = tid % 30;
            const int rg = tid / 30;            // 0..7
            const float* xb = x + ((size_t)n * HIMG + (size_t)(R0 + rg)) * ROWF
                                + (3 * (col0 - 4) + 4 * cg - 4);
            float* hb = hblur + rg * BF + 4 * cg;
            for (int r = rg; r < nrows; r += 8, xb += 8 * ROWF, hb += 8 * BF) {
                const float4 a = *(const float4*)(xb);
                const float4 b = *(const float4*)(xb + 4);
                const float4 c = *(const float4*)(xb + 8);
                float4 o;
                o.x = G0 * (a.y + b.w) + G1 * b.x;
                o.y = G0 * (a.z + c.x) + G1 * b.y;
                o.z = G0 * (a.w + c.y) + G1 * b.z;
                o.w = G0 * (b.x + c.z) + G1 * b.w;
                *(float4*)hb = o;
            }
        }
    } else {
        // Edge-column blocks (2/16): scalar column-LUT path with double-reflect.
        if (tid < 240) {
            const int lc  = tid % BF;
            const int rg  = tid / BF;           // 0 or 1
            const int lcp = lc / 3;
            const int ch  = lc - 3 * lcp;
            const int gc  = reflect101(col0 - 4 + lcp, WIMG);
            const int xm  = reflect101(gc - 1, WIMG) * 3 + ch;
            const int x0  = gc * 3 + ch;
            const int xp  = reflect101(gc + 1, WIMG) * 3 + ch;
            const float* xr = x + ((size_t)n * HIMG + (size_t)(R0 + rg)) * ROWF;
            for (int r = rg; r < nrows; r += 2, xr += 2 * ROWF) {
                hblur[r * BF + lc] = G0 * (xr[xm] + xr[xp]) + G1 * xr[x0];
            }
        }
    }
    __syncthreads();

    // ---- stage 2: vertical 3-tap Gaussian, hblur -> blur (2-row pairs) ----
    // Interior tiles (30/32, block-uniform branch): hblur row h = global row
    // row0-5+h, no reflection; pair (2lp,2lp+1) reads rows 2lp..2lp+3.
    if (row0 > 0 && row0 + TH < HIMG) {
        for (int g = tid; g < 12 * 30; g += 256) {
            const int lp = g / 30;
            const int qc = g - lp * 30;
            const float* hb = hblur + (2 * lp) * BF + qc * 4;
            const float4 w0 = *(const float4*)(hb);
            const float4 w1 = *(const float4*)(hb + BF);
            const float4 w2 = *(const float4*)(hb + 2 * BF);
            const float4 w3 = *(const float4*)(hb + 3 * BF);
            float* bp = blur + (2 * lp) * BF + qc * 4;
            *(float4*)bp        = g3(w0, w1, w2, G0, G1);
            *(float4*)(bp + BF) = g3(w1, w2, w3, G0, G1);
        }
    } else {
        // Boundary tiles: full double-reflect per pair row.
        for (int g = tid; g < 12 * 30; g += 256) {
            const int lp = g / 30;
            const int qc = g - lp * 30;
            const int gg = row0 - 4 + 2 * lp;
            const int y0 = reflect101(gg, HIMG);
            const int y1 = reflect101(gg + 1, HIMG);
            const int lc = qc * 4;
            const float4 a0 = *(const float4*)&hblur[(reflect101(y0 - 1, HIMG) - R0) * BF + lc];
            const float4 a1 = *(const float4*)&hblur[(y0 - R0) * BF + lc];
            const float4 a2 = *(const float4*)&hblur[(reflect101(y0 + 1, HIMG) - R0) * BF + lc];
            const float4 b0 = *(const float4*)&hblur[(reflect101(y1 - 1, HIMG) - R0) * BF + lc];
            const float4 b1 = *(const float4*)&hblur[(y1 - R0) * BF + lc];
            const float4 b2 = *(const float4*)&hblur[(reflect101(y1 + 1, HIMG) - R0) * BF + lc];
            float* bp = blur + (2 * lp) * BF + lc;
            *(float4*)bp        = g3(a0, a1, a2, G0, G1);
            *(float4*)(bp + BF) = g3(b0, b1, b2, G0, G1);
        }
    }
    __syncthreads();   // hblur dead beyond this point

    // ---- stage 3a: vertical 7-tap C6, blur -> vq (2-row register block) ----
    for (int g = tid; g < 9 * 30; g += 256) {
        const int lp = g / 30;
        const int qc = g - lp * 30;
        const float* bp = blur + (2 * lp) * BF + qc * 4;
        float4 w[8];
        #pragma unroll
        for (int k = 0; k < 8; ++k)
            w[k] = *(const float4*)(bp + k * BF);
        float* vp = vq + (2 * lp) * VW + qc * 4;
        *(float4*)vp        = c6dot4(w[0], w[1], w[2], w[3], w[4], w[5], w[6]);
        *(float4*)(vp + VW) = c6dot4(w[1], w[2], w[3], w[4], w[5], w[6], w[7]);
    }
    __syncthreads();   // blur dead beyond this point (P overwrites it)

    // ---- stage 3b: horizontal 7-tap C6, vq -> P (8 outputs/lane) ----
    // P[r][ps] = sum_k C6[k]*vq[r][ps+3k]; ps in [0,104), valid ps <= 101.
    // Reads floats 8qp..8qp+27 (7 chunks); cols 120..123 of vq are garbage but
    // in-bounds; resulting P cols 102..103 are never consumed by stage 3c.
    for (int g = tid; g < PH * 13; g += 256) {
        const int r  = g / 13;
        const int qp = g - r * 13;
        const float* v = vq + r * VW + qp * 8;
        float f[28];
        #pragma unroll
        for (int q = 0; q < 7; ++q) {
            const float4 w = *(const float4*)(v + 4 * q);
            f[4*q+0] = w.x; f[4*q+1] = w.y; f[4*q+2] = w.z; f[4*q+3] = w.w;
        }
        float p[8];
        #pragma unroll
        for (int j = 0; j < 8; ++j)
            p[j] = c6dot(f[j], f[j+3], f[j+6], f[j+9], f[j+12], f[j+15], f[j+18]);
        float* pr = P + r * PW + qp * 8;
        *(float4*)pr       = make_float4(p[0], p[1], p[2], p[3]);
        *(float4*)(pr + 4) = make_float4(p[4], p[5], p[6], p[7]);
    }
    __syncthreads();

    // ---- stage 3c: 5-point cross on P, +1, clip, store (8 outputs/lane) ----
    // out[i][o] = 2*(P[i][o]+P[i][o+6]+P[i+2][o]+P[i+2][o+6]) - 8*P[i+1][o+3] + 1
    // computed as differences-from-center to limit cancellation error.
    float* const outn = out + (size_t)n * HIMG * ROWF;
    for (int g = tid; g < TH * 12; g += 256) {
        const int i  = g / 12;
        const int qp = g - i * 12;
        const int o  = qp * 8;
        const float* pt = P + i * PW + o;
        const float* pm = pt + PW;
        const float* pb = pm + PW;
        float t[16], m[16], b[16];
        #pragma unroll
        for (int q = 0; q < 4; ++q) {
            const float4 vt = *(const float4*)(pt + 4 * q);
            t[4*q+0] = vt.x; t[4*q+1] = vt.y; t[4*q+2] = vt.z; t[4*q+3] = vt.w;
            const float4 vm = *(const float4*)(pm + 4 * q);
            m[4*q+0] = vm.x; m[4*q+1] = vm.y; m[4*q+2] = vm.z; m[4*q+3] = vm.w;
            const float4 vb = *(const float4*)(pb + 4 * q);
            b[4*q+0] = vb.x; b[4*q+1] = vb.y; b[4*q+2] = vb.z; b[4*q+3] = vb.w;
        }
        float o8[8];
        #pragma unroll
        for (int j = 0; j < 8; ++j) {
            const float c = m[j + 3];
            const float s = (t[j] - c) + (t[j + 6] - c) + (b[j] - c) + (b[j + 6] - c);
            const float v = fmaf(2.f, s, 1.f);
            o8[j] = fminf(fmaxf(v, 0.f), 255.f);
        }
        float* op = outn + (size_t)(row0 + i) * ROWF + (size_t)(col0 * 3 + o);
        *(float4*)op       = make_float4(o8[0], o8[1], o8[2], o8[3]);
        *(float4*)(op + 4) = make_float4(o8[4], o8[5], o8[6], o8[7]);
    }
}

extern "C" void kernel_launch(void* const* d_in, const int* in_sizes, int n_in,
                              void* d_out, int out_size, void* d_ws, size_t ws_size,
                              hipStream_t stream) {
    const float* x = (const float*)d_in[0];
    float* outp = (float*)d_out;
    const int nimg = in_sizes[0] / (HIMG * WIMG * 3);
    dim3 grid(WIMG / TW, HIMG / TH, nimg);
    log_fused<<<grid, dim3(256, 1, 1), 0, stream>>>(x, outp);
}